// Round 1
// baseline (1350.428 us; speedup 1.0000x reference)
//
#include <hip/hip_runtime.h>

#define S_ 1024
#define D_ 512

// ---------------------------------------------------------------------------
// GEMM + bias + activation.  C[m,n] = act(sum_k A[m,k]*B[k,n] + bias[n])
// MODE 0: proj   A=x   (lda 512),  B=W_in (ldb 2048), N=1536, tanh for n<1024
// MODE 1: gates  A=v   (lda 1536), B=W_ig/W_fg/W_og (ldb 512), sigmoid
// MODE 2: out    A=hs  (lda 512),  B=W_out (ldb 512), N=512, no act
// BM=BN=128, BK=16, 256 threads, 8x8 micro-tile.
// ---------------------------------------------------------------------------
template<int MODE>
__global__ __launch_bounds__(256)
void gemm_act(const float* __restrict__ A, int lda,
              const float* __restrict__ W0, const float* __restrict__ W1,
              const float* __restrict__ W2,
              const float* __restrict__ bb0, const float* __restrict__ bb1,
              const float* __restrict__ bb2,
              float* __restrict__ Co, int ldc)
{
    const int tid = threadIdx.x;
    const int n0  = blockIdx.x * 128;
    const int m0  = blockIdx.y * 128;

    const float* Bp; const float* bias; int ldb;
    if (MODE == 1) {
        const int g  = n0 >> 9;
        const int nn = n0 & 511;
        Bp   = (g == 0 ? W0 : g == 1 ? W1 : W2) + nn;
        bias = (g == 0 ? bb0 : g == 1 ? bb1 : bb2) + nn;
        ldb  = 512;
    } else {
        Bp   = W0 + n0;
        bias = bb0 + n0;
        ldb  = (MODE == 0 ? 2048 : 512);
    }

    __shared__ float As[16][128];   // K-major
    __shared__ float Bs[16][128];

    float acc[8][8];
#pragma unroll
    for (int i = 0; i < 8; ++i)
#pragma unroll
        for (int j = 0; j < 8; ++j) acc[i][j] = 0.f;

    const int ar = tid >> 2;           // 0..63  (A row within tile, +64 for 2nd)
    const int ac = (tid & 3) * 4;      // 0,4,8,12 (k offset)
    const int br = tid >> 5;           // 0..7   (B k-row, +8 for 2nd)
    const int bc = (tid & 31) * 4;     // col
    const int ty = tid >> 4;           // 0..15
    const int tx = tid & 15;           // 0..15

    const float* Ap = A + (size_t)(m0 + ar) * lda + ac;
    const float* Bq = Bp + (size_t)br * ldb + bc;

    for (int k0 = 0; k0 < 512; k0 += 16) {
        float4 a0 = *(const float4*)(Ap);
        float4 a1 = *(const float4*)(Ap + (size_t)64 * lda);
        float4 b0 = *(const float4*)(Bq);
        float4 b1 = *(const float4*)(Bq + (size_t)8 * ldb);
        Ap += 16; Bq += (size_t)16 * ldb;

        __syncthreads();   // previous compute done before overwriting LDS
        As[ac + 0][ar]      = a0.x; As[ac + 1][ar]      = a0.y;
        As[ac + 2][ar]      = a0.z; As[ac + 3][ar]      = a0.w;
        As[ac + 0][ar + 64] = a1.x; As[ac + 1][ar + 64] = a1.y;
        As[ac + 2][ar + 64] = a1.z; As[ac + 3][ar + 64] = a1.w;
        *(float4*)&Bs[br][bc]     = b0;
        *(float4*)&Bs[br + 8][bc] = b1;
        __syncthreads();

#pragma unroll
        for (int kk = 0; kk < 16; ++kk) {
            float4 aL = *(const float4*)&As[kk][ty * 4];
            float4 aH = *(const float4*)&As[kk][64 + ty * 4];
            float4 bL = *(const float4*)&Bs[kk][tx * 4];
            float4 bH = *(const float4*)&Bs[kk][64 + tx * 4];
            float av[8] = {aL.x, aL.y, aL.z, aL.w, aH.x, aH.y, aH.z, aH.w};
            float bv[8] = {bL.x, bL.y, bL.z, bL.w, bH.x, bH.y, bH.z, bH.w};
#pragma unroll
            for (int i = 0; i < 8; ++i)
#pragma unroll
                for (int j = 0; j < 8; ++j)
                    acc[i][j] = fmaf(av[i], bv[j], acc[i][j]);
        }
    }

    // epilogue
    float bv[8];
#pragma unroll
    for (int j = 0; j < 8; ++j) {
        const int c = (j < 4) ? (tx * 4 + j) : (64 + tx * 4 + j - 4);
        bv[j] = bias[c];
    }
#pragma unroll
    for (int i = 0; i < 8; ++i) {
        const int m = m0 + ((i < 4) ? (ty * 4 + i) : (64 + ty * 4 + i - 4));
        float vals[8];
#pragma unroll
        for (int j = 0; j < 8; ++j) {
            float v = acc[i][j] + bv[j];
            if (MODE == 0) {
                const int cg = n0 + ((j < 4) ? (tx * 4 + j) : (64 + tx * 4 + j - 4));
                if (cg < 1024) v = tanhf(v);
            } else if (MODE == 1) {
                v = 1.0f / (1.0f + expf(-v));
            }
            vals[j] = v;
        }
        float* row = Co + (size_t)m * ldc + n0;
        *(float4*)&row[tx * 4]      = make_float4(vals[0], vals[1], vals[2], vals[3]);
        *(float4*)&row[64 + tx * 4] = make_float4(vals[4], vals[5], vals[6], vals[7]);
    }
}

// ---------------------------------------------------------------------------
// Recurrent scan.  grid = 8 batches x 32 e-blocks (256 WGs, 256 thr).
// Wave w owns e-columns e0..e0+3 and ALL 512 d-rows (8 rows/lane:
// d = 2*lane + 128*r + {0,1}).  C resident in registers, n/denom in f64.
// No __syncthreads in the time loop; h-reduction is wave-local shuffles.
// ---------------------------------------------------------------------------
__global__ __launch_bounds__(256)
void scan_kernel(const float* __restrict__ QKV, const float* __restrict__ GG,
                 float* __restrict__ hs, float* __restrict__ CfO,
                 float* __restrict__ nfO, float* __restrict__ hlO)
{
    const int tid  = threadIdx.x;
    const int lane = tid & 63;
    const int w    = tid >> 6;
    const int bid  = blockIdx.x;
    const int b    = bid >> 5;
    const int e0   = (bid & 31) * 16 + w * 4;
    const int d0   = 2 * lane;

    const float* qb = QKV + (size_t)b * S_ * 1536;
    const float* gb = GG  + (size_t)b * S_ * 1536;

    float Cr0[4][4], Cr1[4][4];     // rows d0+128r (+0 / +1), cols e0..e0+3
    double nr[8];
#pragma unroll
    for (int r = 0; r < 4; ++r) {
#pragma unroll
        for (int j = 0; j < 4; ++j) { Cr0[r][j] = 0.f; Cr1[r][j] = 0.f; }
        nr[2 * r] = 0.0; nr[2 * r + 1] = 0.0;
    }

    float2 q2[4], k2[4], i2[4], f2[4]; float4 v4, o4;
    {
        const float* r1 = qb;
        const float* r2 = gb;
#pragma unroll
        for (int r = 0; r < 4; ++r) {
            q2[r] = *(const float2*)(r1 + d0 + 128 * r);
            k2[r] = *(const float2*)(r1 + 512 + d0 + 128 * r);
            i2[r] = *(const float2*)(r2 + d0 + 128 * r);
            f2[r] = *(const float2*)(r2 + 512 + d0 + 128 * r);
        }
        v4 = *(const float4*)(r1 + 1024 + e0);
        o4 = *(const float4*)(r2 + 1024 + e0);
    }

    for (int t = 0; t < S_; ++t) {
        float2 qn[4], kn[4], in_[4], fn[4]; float4 vn, on;
        if (t + 1 < S_) {       // prefetch next step
            const float* r1 = qb + (size_t)(t + 1) * 1536;
            const float* r2 = gb + (size_t)(t + 1) * 1536;
#pragma unroll
            for (int r = 0; r < 4; ++r) {
                qn[r]  = *(const float2*)(r1 + d0 + 128 * r);
                kn[r]  = *(const float2*)(r1 + 512 + d0 + 128 * r);
                in_[r] = *(const float2*)(r2 + d0 + 128 * r);
                fn[r]  = *(const float2*)(r2 + 512 + d0 + 128 * r);
            }
            vn = *(const float4*)(r1 + 1024 + e0);
            on = *(const float4*)(r2 + 1024 + e0);
        }

        float p0 = 0.f, p1 = 0.f, p2 = 0.f, p3 = 0.f;
        double dq = 0.0;
#pragma unroll
        for (int r = 0; r < 4; ++r) {
            const float ik0 = i2[r].x * k2[r].x;
            const float ik1 = i2[r].y * k2[r].y;
            nr[2 * r]     = fma((double)f2[r].x, nr[2 * r],     (double)ik0);
            nr[2 * r + 1] = fma((double)f2[r].y, nr[2 * r + 1], (double)ik1);
            dq = fma((double)q2[r].x, nr[2 * r],     dq);
            dq = fma((double)q2[r].y, nr[2 * r + 1], dq);
            const float f0 = f2[r].x, f1 = f2[r].y;
            Cr0[r][0] = fmaf(f0, Cr0[r][0], ik0 * v4.x);
            Cr0[r][1] = fmaf(f0, Cr0[r][1], ik0 * v4.y);
            Cr0[r][2] = fmaf(f0, Cr0[r][2], ik0 * v4.z);
            Cr0[r][3] = fmaf(f0, Cr0[r][3], ik0 * v4.w);
            Cr1[r][0] = fmaf(f1, Cr1[r][0], ik1 * v4.x);
            Cr1[r][1] = fmaf(f1, Cr1[r][1], ik1 * v4.y);
            Cr1[r][2] = fmaf(f1, Cr1[r][2], ik1 * v4.z);
            Cr1[r][3] = fmaf(f1, Cr1[r][3], ik1 * v4.w);
            p0 = fmaf(q2[r].x, Cr0[r][0], p0); p0 = fmaf(q2[r].y, Cr1[r][0], p0);
            p1 = fmaf(q2[r].x, Cr0[r][1], p1); p1 = fmaf(q2[r].y, Cr1[r][1], p1);
            p2 = fmaf(q2[r].x, Cr0[r][2], p2); p2 = fmaf(q2[r].y, Cr1[r][2], p2);
            p3 = fmaf(q2[r].x, Cr0[r][3], p3); p3 = fmaf(q2[r].y, Cr1[r][3], p3);
        }

        // h_cand: fold-reduce 4 values over 64 lanes
        float u0 = p0 + __shfl_xor(p0, 32);
        float u1 = p1 + __shfl_xor(p1, 32);
        float u2 = p2 + __shfl_xor(p2, 32);
        float u3 = p3 + __shfl_xor(p3, 32);
        const bool hb = (lane & 32) != 0;
        float w0 = hb ? u2 : u0;
        float w1 = hb ? u3 : u1;
        float x0 = w0 + __shfl_xor(w0, 16);
        float x1 = w1 + __shfl_xor(w1, 16);
        float z  = (lane & 16) ? x1 : x0;
        z += __shfl_xor(z, 8); z += __shfl_xor(z, 4);
        z += __shfl_xor(z, 2); z += __shfl_xor(z, 1);
        // lanes {0,16,32,48} hold h_cand[e0 + (lane>>4)]

        // denom: full butterfly in f64
        double s = dq;
        s += __shfl_xor(s, 32); s += __shfl_xor(s, 16); s += __shfl_xor(s, 8);
        s += __shfl_xor(s, 4);  s += __shfl_xor(s, 2);  s += __shfl_xor(s, 1);
        const double denom = (s > 1e-6) ? s : 1e-6;

        if ((lane & 15) == 0) {
            const int idx = lane >> 4;
            const float oe = (idx == 0) ? o4.x : (idx == 1) ? o4.y
                           : (idx == 2) ? o4.z : o4.w;
            const float h = (float)((double)oe * (double)z / denom);
            hs[((size_t)(b * S_ + t)) * 512 + e0 + idx] = h;
            if (t == S_ - 1) hlO[(size_t)b * 512 + e0 + idx] = h;
        }

        if (t + 1 < S_) {
#pragma unroll
            for (int r = 0; r < 4; ++r) {
                q2[r] = qn[r]; k2[r] = kn[r]; i2[r] = in_[r]; f2[r] = fn[r];
            }
            v4 = vn; o4 = on;
        }
    }

    // final states
#pragma unroll
    for (int r = 0; r < 4; ++r) {
        const int d = d0 + 128 * r;
        *(float4*)&CfO[((size_t)b * 512 + d) * 512 + e0] =
            make_float4(Cr0[r][0], Cr0[r][1], Cr0[r][2], Cr0[r][3]);
        *(float4*)&CfO[((size_t)b * 512 + d + 1) * 512 + e0] =
            make_float4(Cr1[r][0], Cr1[r][1], Cr1[r][2], Cr1[r][3]);
    }
    if ((bid & 31) == 0 && w == 0) {
#pragma unroll
        for (int r = 0; r < 4; ++r) {
            nfO[(size_t)b * 512 + d0 + 128 * r]     = (float)nr[2 * r];
            nfO[(size_t)b * 512 + d0 + 128 * r + 1] = (float)nr[2 * r + 1];
        }
    }
}

// ---------------------------------------------------------------------------
extern "C" void kernel_launch(void* const* d_in, const int* in_sizes, int n_in,
                              void* d_out, int out_size, void* d_ws, size_t ws_size,
                              hipStream_t stream)
{
    const float* x    = (const float*)d_in[0];
    const float* W_in = (const float*)d_in[1];
    const float* b_in = (const float*)d_in[2];
    const float* W_ig = (const float*)d_in[3];
    const float* b_ig = (const float*)d_in[4];
    const float* W_fg = (const float*)d_in[5];
    const float* b_fg = (const float*)d_in[6];
    const float* W_og = (const float*)d_in[7];
    const float* b_og = (const float*)d_in[8];
    const float* W_out= (const float*)d_in[9];
    const float* b_out= (const float*)d_in[10];

    float* out   = (float*)d_out;                       // [8,1024,512]
    float* CfO   = out + (size_t)8 * 1024 * 512;        // [8,512,512]
    float* nfO   = CfO + (size_t)8 * 512 * 512;         // [8,512]
    float* hlO   = nfO + (size_t)8 * 512;               // [8,512]

    float* qkv = (float*)d_ws;                          // [8192,1536] q|k|v
    float* gg  = qkv + (size_t)8192 * 1536;             // [8192,1536] i|f|o
    float* hsb = gg  + (size_t)8192 * 1536;             // [8192,512]

    // 1. proj + tanh(q,k) (cols 1536..2047 of W_in are dead)
    gemm_act<0><<<dim3(12, 64), 256, 0, stream>>>(
        x, 512, W_in, W_in, W_in, b_in, b_in, b_in, qkv, 1536);
    // 2. gates = sigmoid(v @ [W_ig|W_fg|W_og])
    gemm_act<1><<<dim3(12, 64), 256, 0, stream>>>(
        qkv + 1024, 1536, W_ig, W_fg, W_og, b_ig, b_fg, b_og, gg, 1536);
    // 3. recurrent scan
    scan_kernel<<<256, 256, 0, stream>>>(qkv, gg, hsb, CfO, nfO, hlO);
    // 4. out = hs @ W_out + b_out
    gemm_act<2><<<dim3(4, 64), 256, 0, stream>>>(
        hsb, 512, W_out, W_out, W_out, b_out, b_out, b_out, out, 512);
}

// Round 2
// 1206.930 us; speedup vs baseline: 1.1189x; 1.1189x over previous
//
#include <hip/hip_runtime.h>

#define S_ 1024
#define D_ 512
#define CHUNK 64
#define NCH 16

// ---------------------------------------------------------------------------
// GEMM + bias + activation.  C[m,n] = act(sum_k A[m,k]*B[k,n] + bias[n])
// MODE 0: proj   A=x   (lda 512),  B=W_in (ldb 2048), N=1536, tanh for n<1024
// MODE 1: gates  A=v   (lda 1536), B=W_ig/W_fg/W_og (ldb 512), sigmoid;
//                g==0 (i-gate) is fused to i*k (k read from qkv).
// MODE 2: out    A=hs  (lda 512),  B=W_out (ldb 512), N=512, no act
// ---------------------------------------------------------------------------
template<int MODE>
__global__ __launch_bounds__(256)
void gemm_act(const float* __restrict__ A, int lda,
              const float* __restrict__ W0, const float* __restrict__ W1,
              const float* __restrict__ W2,
              const float* __restrict__ bb0, const float* __restrict__ bb1,
              const float* __restrict__ bb2,
              float* __restrict__ Co, int ldc)
{
    const int tid = threadIdx.x;
    const int n0  = blockIdx.x * 128;
    const int m0  = blockIdx.y * 128;

    const float* Bp; const float* bias; int ldb;
    if (MODE == 1) {
        const int g  = n0 >> 9;
        const int nn = n0 & 511;
        Bp   = (g == 0 ? W0 : g == 1 ? W1 : W2) + nn;
        bias = (g == 0 ? bb0 : g == 1 ? bb1 : bb2) + nn;
        ldb  = 512;
    } else {
        Bp   = W0 + n0;
        bias = bb0 + n0;
        ldb  = (MODE == 0 ? 2048 : 512);
    }

    __shared__ float As[16][128];   // K-major
    __shared__ float Bs[16][128];

    float acc[8][8];
#pragma unroll
    for (int i = 0; i < 8; ++i)
#pragma unroll
        for (int j = 0; j < 8; ++j) acc[i][j] = 0.f;

    const int ar = tid >> 2;
    const int ac = (tid & 3) * 4;
    const int br = tid >> 5;
    const int bc = (tid & 31) * 4;
    const int ty = tid >> 4;
    const int tx = tid & 15;

    const float* Ap = A + (size_t)(m0 + ar) * lda + ac;
    const float* Bq = Bp + (size_t)br * ldb + bc;

    for (int k0 = 0; k0 < 512; k0 += 16) {
        float4 a0 = *(const float4*)(Ap);
        float4 a1 = *(const float4*)(Ap + (size_t)64 * lda);
        float4 b0 = *(const float4*)(Bq);
        float4 b1 = *(const float4*)(Bq + (size_t)8 * ldb);
        Ap += 16; Bq += (size_t)16 * ldb;

        __syncthreads();
        As[ac + 0][ar]      = a0.x; As[ac + 1][ar]      = a0.y;
        As[ac + 2][ar]      = a0.z; As[ac + 3][ar]      = a0.w;
        As[ac + 0][ar + 64] = a1.x; As[ac + 1][ar + 64] = a1.y;
        As[ac + 2][ar + 64] = a1.z; As[ac + 3][ar + 64] = a1.w;
        *(float4*)&Bs[br][bc]     = b0;
        *(float4*)&Bs[br + 8][bc] = b1;
        __syncthreads();

#pragma unroll
        for (int kk = 0; kk < 16; ++kk) {
            float4 aL = *(const float4*)&As[kk][ty * 4];
            float4 aH = *(const float4*)&As[kk][64 + ty * 4];
            float4 bL = *(const float4*)&Bs[kk][tx * 4];
            float4 bH = *(const float4*)&Bs[kk][64 + tx * 4];
            float av[8] = {aL.x, aL.y, aL.z, aL.w, aH.x, aH.y, aH.z, aH.w};
            float bv[8] = {bL.x, bL.y, bL.z, bL.w, bH.x, bH.y, bH.z, bH.w};
#pragma unroll
            for (int i = 0; i < 8; ++i)
#pragma unroll
                for (int j = 0; j < 8; ++j)
                    acc[i][j] = fmaf(av[i], bv[j], acc[i][j]);
        }
    }

    float bv[8];
#pragma unroll
    for (int j = 0; j < 8; ++j) {
        const int c = (j < 4) ? (tx * 4 + j) : (64 + tx * 4 + j - 4);
        bv[j] = bias[c];
    }
#pragma unroll
    for (int i = 0; i < 8; ++i) {
        const int m = m0 + ((i < 4) ? (ty * 4 + i) : (64 + ty * 4 + i - 4));
        float vals[8];
#pragma unroll
        for (int j = 0; j < 8; ++j) {
            float v = acc[i][j] + bv[j];
            if (MODE == 0) {
                const int cg = n0 + ((j < 4) ? (tx * 4 + j) : (64 + tx * 4 + j - 4));
                if (cg < 1024) v = tanhf(v);
            } else if (MODE == 1) {
                v = 1.0f / (1.0f + expf(-v));
            }
            vals[j] = v;
        }
        if (MODE == 1 && n0 < 512) {
            // fuse i_g -> i_g * k   (k lives 512 floats before v in the qkv row)
            const float* krow = A + (size_t)m * lda - 512;
            float4 kl = *(const float4*)(krow + n0 + tx * 4);
            float4 kh = *(const float4*)(krow + n0 + 64 + tx * 4);
            vals[0] *= kl.x; vals[1] *= kl.y; vals[2] *= kl.z; vals[3] *= kl.w;
            vals[4] *= kh.x; vals[5] *= kh.y; vals[6] *= kh.z; vals[7] *= kh.w;
        }
        float* row = Co + (size_t)m * ldc + n0;
        *(float4*)&row[tx * 4]      = make_float4(vals[0], vals[1], vals[2], vals[3]);
        *(float4*)&row[64 + tx * 4] = make_float4(vals[4], vals[5], vals[6], vals[7]);
    }
}

// ---------------------------------------------------------------------------
// n-scan / denominator pipeline (f64 throughout, semantics == R1's in-scan f64)
// D1: per-(b,chunk) local scan with n0=0; store end-state n and decay product.
// D2: sequential stitch over 16 chunks -> chunk seeds n0a + final n output.
// D3: replay each chunk seeded with n0a; per-step f64 dot q.n -> inv_denom.
// ---------------------------------------------------------------------------
__global__ __launch_bounds__(512)
void nscan_local(const float* __restrict__ GG,
                 double* __restrict__ nend, double* __restrict__ Dend)
{
    const int b = blockIdx.x >> 4;
    const int c = blockIdx.x & 15;
    const int d = threadIdx.x;
    const float* gb = GG + (size_t)b * S_ * 1536 + (size_t)c * CHUNK * 1536;
    double n = 0.0, P = 1.0;
    for (int u = 0; u < CHUNK; ++u) {
        const float* row = gb + (size_t)u * 1536;
        const double ik = (double)row[d];          // ik pre-fused in gates GEMM
        const double f  = (double)row[512 + d];
        n = fma(f, n, ik);
        P *= f;
    }
    nend[(size_t)blockIdx.x * 512 + d] = n;
    Dend[(size_t)blockIdx.x * 512 + d] = P;
}

__global__ __launch_bounds__(512)
void nscan_stitch(const double* __restrict__ nend, const double* __restrict__ Dend,
                  double* __restrict__ n0a, float* __restrict__ nfO)
{
    const int b = blockIdx.x;
    const int d = threadIdx.x;
    double n0 = 0.0;
    for (int c = 0; c < NCH; ++c) {
        const size_t idx = ((size_t)(b * NCH + c)) * 512 + d;
        n0a[idx] = n0;
        n0 = fma(Dend[idx], n0, nend[idx]);
    }
    nfO[(size_t)b * 512 + d] = (float)n0;
}

__global__ __launch_bounds__(512)
void denom_kernel(const float* __restrict__ QKV, const float* __restrict__ GG,
                  const double* __restrict__ n0a, float* __restrict__ invd)
{
    const int b    = blockIdx.x >> 4;
    const int c    = blockIdx.x & 15;
    const int d    = threadIdx.x;
    const int lane = d & 63;
    const int w    = d >> 6;
    __shared__ double sm[8];
    const float* qb = QKV + (size_t)b * S_ * 1536 + (size_t)c * CHUNK * 1536;
    const float* gb = GG  + (size_t)b * S_ * 1536 + (size_t)c * CHUNK * 1536;
    double n = n0a[(size_t)blockIdx.x * 512 + d];
    for (int u = 0; u < CHUNK; ++u) {
        const float* qr = qb + (size_t)u * 1536;
        const float* gr = gb + (size_t)u * 1536;
        n = fma((double)gr[512 + d], n, (double)gr[d]);
        double s = (double)qr[d] * n;
        s += __shfl_xor(s, 32); s += __shfl_xor(s, 16); s += __shfl_xor(s, 8);
        s += __shfl_xor(s, 4);  s += __shfl_xor(s, 2);  s += __shfl_xor(s, 1);
        if (lane == 0) sm[w] = s;
        __syncthreads();
        if (d == 0) {
            double tot = sm[0] + sm[1] + sm[2] + sm[3]
                       + sm[4] + sm[5] + sm[6] + sm[7];
            const double den = (tot > 1e-6) ? tot : 1e-6;
            invd[(size_t)b * S_ + c * CHUNK + u] = (float)(1.0 / den);
        }
        __syncthreads();
    }
}

// ---------------------------------------------------------------------------
// Recurrent scan.  grid = 512 blocks (b = bid&7 -> XCD-local batches),
// 4 waves/block, each wave owns 2 e-cols x all 512 d.
// lane d-mapping: d = 4*lane + j + 256*r  (float4-coalesced loads).
// C register-resident; denominators precomputed -> no f64, no div in loop.
// ---------------------------------------------------------------------------
__global__ __launch_bounds__(256)
void scan_kernel(const float* __restrict__ QKV, const float* __restrict__ GG,
                 const float* __restrict__ invd,
                 float* __restrict__ hs, float* __restrict__ CfO,
                 float* __restrict__ hlO)
{
    const int tid  = threadIdx.x;
    const int lane = tid & 63;
    const int w    = tid >> 6;
    const int bid  = blockIdx.x;
    const int b    = bid & 7;                 // batch == XCD (round-robin)
    const int e0   = (bid >> 3) * 8 + w * 2;
    const int d0   = 4 * lane;

    const float* qb  = QKV + (size_t)b * S_ * 1536;
    const float* gb  = GG  + (size_t)b * S_ * 1536;
    const float* ivb = invd + (size_t)b * S_;

    float C[2][4][2];
#pragma unroll
    for (int r = 0; r < 2; ++r)
#pragma unroll
        for (int j = 0; j < 4; ++j) { C[r][j][0] = 0.f; C[r][j][1] = 0.f; }

    float4 q4[2], f4[2], ik4[2]; float2 v2, o2; float iv;
    {
        const float* r1 = qb; const float* r2 = gb;
#pragma unroll
        for (int r = 0; r < 2; ++r) {
            q4[r]  = *(const float4*)(r1 + d0 + 256 * r);
            f4[r]  = *(const float4*)(r2 + 512 + d0 + 256 * r);
            ik4[r] = *(const float4*)(r2 + d0 + 256 * r);
        }
        v2 = *(const float2*)(r1 + 1024 + e0);
        o2 = *(const float2*)(r2 + 1024 + e0);
        iv = ivb[0];
    }

    for (int t = 0; t < S_; ++t) {
        float4 qn[2], fn[2], ikn[2]; float2 vn, on; float ivn;
        if (t + 1 < S_) {
            const float* r1 = qb + (size_t)(t + 1) * 1536;
            const float* r2 = gb + (size_t)(t + 1) * 1536;
#pragma unroll
            for (int r = 0; r < 2; ++r) {
                qn[r]  = *(const float4*)(r1 + d0 + 256 * r);
                fn[r]  = *(const float4*)(r2 + 512 + d0 + 256 * r);
                ikn[r] = *(const float4*)(r2 + d0 + 256 * r);
            }
            vn  = *(const float2*)(r1 + 1024 + e0);
            on  = *(const float2*)(r2 + 1024 + e0);
            ivn = ivb[t + 1];
        }

        float p0 = 0.f, p1 = 0.f;
#pragma unroll
        for (int r = 0; r < 2; ++r) {
            const float* qp = (const float*)&q4[r];
            const float* fp = (const float*)&f4[r];
            const float* kp = (const float*)&ik4[r];
#pragma unroll
            for (int j = 0; j < 4; ++j) {
                const float ik = kp[j], ff = fp[j], qq = qp[j];
                C[r][j][0] = fmaf(ff, C[r][j][0], ik * v2.x);
                C[r][j][1] = fmaf(ff, C[r][j][1], ik * v2.y);
                p0 = fmaf(qq, C[r][j][0], p0);
                p1 = fmaf(qq, C[r][j][1], p1);
            }
        }

        // reduce two dot products over 64 lanes: fold + 5-step butterfly
        float a  = p0 + __shfl_xor(p0, 32);
        float bb = p1 + __shfl_xor(p1, 32);
        float cc = (lane & 32) ? bb : a;
        cc += __shfl_xor(cc, 16);
        cc += __shfl_xor(cc, 8);
        cc += __shfl_xor(cc, 4);
        cc += __shfl_xor(cc, 2);
        cc += __shfl_xor(cc, 1);

        if ((lane & 31) == 0) {
            const int ei = lane >> 5;
            const float oe = ei ? o2.y : o2.x;
            const float h = oe * cc * iv;
            hs[((size_t)(b * S_ + t)) * 512 + e0 + ei] = h;
            if (t == S_ - 1) hlO[(size_t)b * 512 + e0 + ei] = h;
        }

        if (t + 1 < S_) {
#pragma unroll
            for (int r = 0; r < 2; ++r) { q4[r] = qn[r]; f4[r] = fn[r]; ik4[r] = ikn[r]; }
            v2 = vn; o2 = on; iv = ivn;
        }
    }

#pragma unroll
    for (int r = 0; r < 2; ++r)
#pragma unroll
        for (int j = 0; j < 4; ++j) {
            const int d = d0 + j + 256 * r;
            *(float2*)&CfO[((size_t)b * 512 + d) * 512 + e0] =
                make_float2(C[r][j][0], C[r][j][1]);
        }
}

// ---------------------------------------------------------------------------
extern "C" void kernel_launch(void* const* d_in, const int* in_sizes, int n_in,
                              void* d_out, int out_size, void* d_ws, size_t ws_size,
                              hipStream_t stream)
{
    const float* x    = (const float*)d_in[0];
    const float* W_in = (const float*)d_in[1];
    const float* b_in = (const float*)d_in[2];
    const float* W_ig = (const float*)d_in[3];
    const float* b_ig = (const float*)d_in[4];
    const float* W_fg = (const float*)d_in[5];
    const float* b_fg = (const float*)d_in[6];
    const float* W_og = (const float*)d_in[7];
    const float* b_og = (const float*)d_in[8];
    const float* W_out= (const float*)d_in[9];
    const float* b_out= (const float*)d_in[10];

    float* out   = (float*)d_out;                       // [8,1024,512]
    float* CfO   = out + (size_t)8 * 1024 * 512;        // [8,512,512]
    float* nfO   = CfO + (size_t)8 * 512 * 512;         // [8,512]
    float* hlO   = nfO + (size_t)8 * 512;               // [8,512]

    float* qkv = (float*)d_ws;                          // [8192,1536] q|k|v
    float* gg  = qkv + (size_t)8192 * 1536;             // [8192,1536] ik|f|o
    float* hsb = gg  + (size_t)8192 * 1536;             // [8192,512]
    // transient n-scan scratch overlaid on hsb (dead once scan_kernel runs)
    double* nend = (double*)hsb;                        // [8*16,512] f64
    double* Dend = nend + (size_t)8 * NCH * 512;
    double* n0a  = Dend + (size_t)8 * NCH * 512;
    float*  invd = hsb + (size_t)8192 * 512;            // [8,1024] (+32 KB)

    // 1. proj + tanh(q,k)
    gemm_act<0><<<dim3(12, 64), 256, 0, stream>>>(
        x, 512, W_in, W_in, W_in, b_in, b_in, b_in, qkv, 1536);
    // 2. gates: [i*k | f | o]
    gemm_act<1><<<dim3(12, 64), 256, 0, stream>>>(
        qkv + 1024, 1536, W_ig, W_fg, W_og, b_ig, b_fg, b_og, gg, 1536);
    // 3. n-scan + denominators (f64)
    nscan_local <<<128, 512, 0, stream>>>(gg, nend, Dend);
    nscan_stitch<<<  8, 512, 0, stream>>>(nend, Dend, n0a, nfO);
    denom_kernel<<<128, 512, 0, stream>>>(qkv, gg, n0a, invd);
    // 4. recurrent scan (C only)
    scan_kernel<<<512, 256, 0, stream>>>(qkv, gg, invd, hsb, CfO, hlO);
    // 5. out = hs @ W_out + b_out
    gemm_act<2><<<dim3(4, 64), 256, 0, stream>>>(
        hsb, 512, W_out, W_out, W_out, b_out, b_out, b_out, out, 512);
}